// Round 1
// baseline (83.283 us; speedup 1.0000x reference)
//
#include <hip/hip_runtime.h>

// Problem constants (from reference): BS=8, Q=500, NC=2, T=400
#define P_TOT 4000   // BS*Q
#define T_TOT 400
#define PP    8      // preds per block

__global__ __launch_bounds__(256) void hm_cost_kernel(
    const float* __restrict__ logits,    // [P_TOT, 2]
    const float* __restrict__ kp,        // [P_TOT, 53]
    const int*   __restrict__ tgt_ids,   // [T_TOT]
    const float* __restrict__ tk,        // [T_TOT, 53]
    const int*   __restrict__ num_boxes, // [1]
    float*       __restrict__ out)       // [P_TOT, T_TOT]
{
    const int t     = blockIdx.x * blockDim.x + threadIdx.x;
    const bool valid = (t < T_TOT);
    const int tc    = valid ? t : (T_TOT - 1);   // clamp for safe loads

    const float nbinv = 1.0f / (float)(*num_boxes);   // uniform scalar load

    // ---- pin this thread's target row in registers for the whole block ----
    const float* trow = tk + tc * 53;
    const float Cg0 = trow[0];
    const float Cg1 = trow[1];
    float Zg[34];
#pragma unroll
    for (int k = 0; k < 34; ++k) Zg[k] = trow[2 + k];
    float Vg[17];
#pragma unroll
    for (int j = 0; j < 17; ++j) Vg[j] = trow[36 + j];
    const int cls = tgt_ids[tc];   // in [0, 2)

    const int pbase = blockIdx.y * PP;

#pragma unroll 1
    for (int pi = 0; pi < PP; ++pi) {
        const int p = pbase + pi;                 // uniform across block
        const float* prow = kp + p * 53;          // uniform -> scalar loads

        // 2-class softmax, gather by target class
        const float l0 = logits[p * 2 + 0];
        const float l1 = logits[p * 2 + 1];
        const float m  = fmaxf(l0, l1);
        const float e0 = __expf(l0 - m);
        const float e1 = __expf(l1 - m);
        const float sinv = 1.0f / (e0 + e1);
        const float prob = (cls == 0 ? e0 : e1) * sinv;

        const float dc0 = prow[0] - Cg0;
        const float dc1 = prow[1] - Cg1;

        // offset + abs losses share dz; Vgt in {0,1} so |dz*v| == |dz|*v
        float off = 0.f, ab = 0.f;
#pragma unroll
        for (int j = 0; j < 17; ++j) {
            const float v   = Vg[j];
            const float dz0 = prow[2 + 2 * j]     - Zg[2 * j];
            const float dz1 = prow[2 + 2 * j + 1] - Zg[2 * j + 1];
            off += (fabsf(dz0) + fabsf(dz1)) * v;
            ab  += (fabsf(dz0 + dc0) + fabsf(dz1 + dc1)) * v;
        }

        float viz = 0.f;
#pragma unroll
        for (int j = 0; j < 17; ++j) {
            const float d = prow[36 + j] - Vg[j];
            viz += d * d;
        }

        const float ctr = dc0 * dc0 + dc1 * dc1;

        const float c = -prob
                      + (0.5f * off + 4.0f * ab + 0.2f * viz + 0.5f * ctr) * nbinv;

        if (valid) out[p * T_TOT + t] = c;   // coalesced, t-contiguous
    }
}

extern "C" void kernel_launch(void* const* d_in, const int* in_sizes, int n_in,
                              void* d_out, int out_size, void* d_ws, size_t ws_size,
                              hipStream_t stream) {
    const float* logits    = (const float*)d_in[0];  // pred_logits  [8,500,2]
    const float* kp        = (const float*)d_in[1];  // pred_keypoints [8,500,53]
    const int*   tgt_ids   = (const int*)  d_in[2];  // [400]
    const float* tk        = (const float*)d_in[3];  // tgt_keypoints [400,53]
    const int*   num_boxes = (const int*)  d_in[4];  // scalar
    float*       out       = (float*)d_out;          // [8,500,400] fp32

    dim3 grid((T_TOT + 255) / 256, P_TOT / PP);      // (2, 500)
    hm_cost_kernel<<<grid, 256, 0, stream>>>(logits, kp, tgt_ids, tk, num_boxes, out);
}

// Round 2
// 78.121 us; speedup vs baseline: 1.0661x; 1.0661x over previous
//
#include <hip/hip_runtime.h>

// Problem constants (from reference): BS=8, Q=500, NC=2, T=400
#define P_TOT 4000   // BS*Q
#define T_TOT 400
#define PP    8      // preds per block
#define BD    448    // 7 waves; covers all 400 targets, 10.7% lane waste

__global__ __launch_bounds__(BD, 3) void hm_cost_kernel(
    const float* __restrict__ logits,    // [P_TOT, 2]
    const float* __restrict__ kp,        // [P_TOT, 53]
    const int*   __restrict__ tgt_ids,   // [T_TOT]
    const float* __restrict__ tk,        // [T_TOT, 53]
    const int*   __restrict__ num_boxes, // [1]
    float*       __restrict__ out)       // [P_TOT, T_TOT]
{
    const int t      = threadIdx.x;
    const bool valid = (t < T_TOT);
    const int tc     = valid ? t : (T_TOT - 1);   // clamp for safe loads

    const float nbinv = 1.0f / (float)(*num_boxes);

    // ---- pin this thread's target row in registers for the whole block ----
    const float* trow = tk + tc * 53;
    const float Cg0 = trow[0];
    const float Cg1 = trow[1];
    float Zg[34];
#pragma unroll
    for (int k = 0; k < 34; ++k) Zg[k] = trow[2 + k];
    float Vg[17];
    float sVg = 0.f;   // sum Vg^2 (hoisted out of pred loop)
#pragma unroll
    for (int j = 0; j < 17; ++j) {
        Vg[j] = trow[36 + j];
        sVg += Vg[j] * Vg[j];
    }
    const bool cls1 = (tgt_ids[tc] != 0);

    const int pbase = blockIdx.x * PP;

#pragma unroll 1
    for (int pi = 0; pi < PP; ++pi) {
        const int p = pbase + pi;                 // uniform across block
        const float* prow = kp + p * 53;          // uniform address

        // 2-class softmax with one exp: p0 = 1/(1+e^(l1-l0)), p1 = q*p0
        const float l0 = logits[2 * p];
        const float l1 = logits[2 * p + 1];
        const float q  = __expf(l1 - l0);
        const float p0 = 1.0f / (1.0f + q);
        const float prob = cls1 ? (q * p0) : p0;

        const float dc0 = prow[0] - Cg0;
        const float dc1 = prow[1] - Cg1;

        // fused 17-iter loop: offset L1, abs L1 (shares dz), vis cross-term.
        // Vg in {0,1} >= 0, so |dz*v| == |dz|*v.
        float off = 0.f, ab = 0.f, vv = 0.f, sVp = 0.f;
#pragma unroll
        for (int j = 0; j < 17; ++j) {
            const float v   = Vg[j];
            const float zp0 = prow[2 + 2 * j];
            const float zp1 = prow[3 + 2 * j];
            const float dz0 = zp0 - Zg[2 * j];
            const float dz1 = zp1 - Zg[2 * j + 1];
            off += (fabsf(dz0) + fabsf(dz1)) * v;
            ab  += (fabsf(dz0 + dc0) + fabsf(dz1 + dc1)) * v;
            const float vp = prow[36 + j];
            vv  += vp * v;
            sVp += vp * vp;
        }

        const float viz = sVp - 2.f * vv + sVg;   // sum (Vp - Vg)^2
        const float ctr = dc0 * dc0 + dc1 * dc1;

        const float c = -prob
                      + (0.5f * off + 4.0f * ab + 0.2f * viz + 0.5f * ctr) * nbinv;

        if (valid) out[p * T_TOT + t] = c;        // coalesced, t-contiguous
    }
}

extern "C" void kernel_launch(void* const* d_in, const int* in_sizes, int n_in,
                              void* d_out, int out_size, void* d_ws, size_t ws_size,
                              hipStream_t stream) {
    const float* logits    = (const float*)d_in[0];  // pred_logits    [8,500,2]
    const float* kp        = (const float*)d_in[1];  // pred_keypoints [8,500,53]
    const int*   tgt_ids   = (const int*)  d_in[2];  // [400]
    const float* tk        = (const float*)d_in[3];  // tgt_keypoints  [400,53]
    const int*   num_boxes = (const int*)  d_in[4];  // scalar
    float*       out       = (float*)d_out;          // [8,500,400] fp32

    hm_cost_kernel<<<P_TOT / PP, BD, 0, stream>>>(logits, kp, tgt_ids, tk,
                                                  num_boxes, out);
}